// Round 6
// baseline (18377.756 us; speedup 1.0000x reference)
//
#include <hip/hip_runtime.h>
#include <hip/hip_bf16.h>

#define NCL   300000
#define NLIT  200000
#define HALFL 100000
#define NVAR  100000

#define NB_C  293            // 293*1024 = 300032 >= NCL
#define PAD_C (NB_C*1024)
#define NB_L  196            // 196*1024 = 200704 >= NLIT
#define PAD_L (NB_L*1024)

// ---------------------------------------------------------------- utilities
__global__ void k_init_lh(const float* __restrict__ L0, float* __restrict__ Lh){
  int i = blockIdx.x*256 + threadIdx.x;            // 25,600,000 total
  Lh[i] = L0[i & 127];
}

__global__ void k_zero4(float4* __restrict__ p, int n4){
  int i = blockIdx.x*256 + threadIdx.x;
  if(i < n4) p[i] = make_float4(0.f,0.f,0.f,0.f);
}

// ---------------------------------------------------------------- CSR build
__global__ __launch_bounds__(256) void k_hist(const int* __restrict__ ci, const int* __restrict__ li,
    int* __restrict__ Pc, int* __restrict__ Pl, int ne){
  int e = blockIdx.x*256 + threadIdx.x;
  if(e < ne){ atomicAdd(&Pc[ci[e]], 1); atomicAdd(&Pl[li[e]], 1); }
}

__global__ __launch_bounds__(256) void k_scan_pass1(const int* __restrict__ P, int* __restrict__ psum){
  __shared__ int red[256];
  int t = threadIdx.x;
  int4 v = *(const int4*)&P[blockIdx.x*1024 + t*4];
  red[t] = v.x + v.y + v.z + v.w;
  __syncthreads();
  for(int ofs=128; ofs>0; ofs>>=1){
    if(t < ofs) red[t] += red[t+ofs];
    __syncthreads();
  }
  if(t == 0) psum[blockIdx.x] = red[0];
}

__global__ __launch_bounds__(512) void k_scan_pass2(int* __restrict__ psum, int nb){
  __shared__ int sA[512], sB[512];
  int t = threadIdx.x;
  sA[t] = (t < nb) ? psum[t] : 0;
  __syncthreads();
  int* src = sA; int* dst = sB;
  for(int ofs=1; ofs<512; ofs<<=1){
    int x = src[t];
    if(t >= ofs) x += src[t-ofs];
    dst[t] = x;
    __syncthreads();
    int* tmp = src; src = dst; dst = tmp;
  }
  psum[t] = t ? src[t-1] : 0;    // exclusive
}

__global__ __launch_bounds__(256) void k_scan_pass3(int* __restrict__ P, const int* __restrict__ psum){
  __shared__ int sA[256], sB[256];
  int t = threadIdx.x;
  int base = blockIdx.x*1024 + t*4;
  int4 v = *(const int4*)&P[base];
  int tsum = v.x + v.y + v.z + v.w;
  sA[t] = tsum;
  __syncthreads();
  int* src = sA; int* dst = sB;
  for(int ofs=1; ofs<256; ofs<<=1){
    int x = src[t];
    if(t >= ofs) x += src[t-ofs];
    dst[t] = x;
    __syncthreads();
    int* tmp = src; src = dst; dst = tmp;
  }
  int excl = psum[blockIdx.x] + src[t] - tsum;   // exclusive across whole array
  int4 o;
  o.x = excl;
  o.y = o.x + v.x;
  o.z = o.y + v.y;
  o.w = o.z + v.z;
  *(int4*)&P[base] = o;
}

// After k_fill, P[c] holds END offset of row c; begin(c) = c ? P[c-1] : 0.
__global__ __launch_bounds__(256) void k_fill(const int* __restrict__ ci, const int* __restrict__ li,
    int* __restrict__ Pc, int* __restrict__ Pl, int* __restrict__ clit, int* __restrict__ lcl, int ne){
  int e = blockIdx.x*256 + threadIdx.x;
  if(e < ne){
    int c = ci[e], l = li[e];
    clit[atomicAdd(&Pc[c], 1)] = l;
    lcl [atomicAdd(&Pl[l], 1)] = c;
  }
}

// ------------------- clause side: CSR gather + MLP 256->256->128 -> C (raw)
// 256 threads, 8 clauses/block. LDS 16.5 KB -> 8 blocks/CU (32 waves, 100%).
__global__ __launch_bounds__(256) void k_clause_fused(
    const int* __restrict__ Pc, const int* __restrict__ clit,
    const float* __restrict__ Lh,
    const float* __restrict__ W1, const float* __restrict__ b1,
    const float* __restrict__ W2, const float* __restrict__ b2, float* __restrict__ Y){
  __shared__ float xs[8][256];
  __shared__ float hs[8][256];
  __shared__ int rng[9];
  const int t = threadIdx.x;
  const int r0 = blockIdx.x * 8;

  if(t < 9) rng[t] = (r0 + t == 0) ? 0 : Pc[r0 + t - 1];
  __syncthreads();

  { // gather: t<128 -> direct half (feature t), t>=128 -> flipped half
    const int f = t & 127, hi = t >> 7;
    for(int r=0;r<8;r++){
      float a = 0.f;
      for(int e=rng[r]; e<rng[r+1]; e++){
        int l = clit[e];
        if(hi) l = (l < HALFL) ? l + HALFL : l - HALFL;
        a += Lh[(size_t)l*128 + f];
      }
      xs[r][t] = a;
    }
  }
  __syncthreads();

  { // layer 1: 1 row x 8 cols per thread
    const int r = t >> 5, c0 = (t & 31)*8;
    float h[8];
    #pragma unroll
    for(int cc=0;cc<8;cc++) h[cc] = b1[c0+cc];
    for(int k=0;k<256;k+=4){
      float4 xv = *(const float4*)&xs[r][k];
      float x4[4] = {xv.x, xv.y, xv.z, xv.w};
      #pragma unroll
      for(int kk=0;kk<4;kk++){
        float4 wa = *(const float4*)&W1[(size_t)(k+kk)*256 + c0];
        float4 wb = *(const float4*)&W1[(size_t)(k+kk)*256 + c0 + 4];
        h[0] = fmaf(x4[kk], wa.x, h[0]); h[1] = fmaf(x4[kk], wa.y, h[1]);
        h[2] = fmaf(x4[kk], wa.z, h[2]); h[3] = fmaf(x4[kk], wa.w, h[3]);
        h[4] = fmaf(x4[kk], wb.x, h[4]); h[5] = fmaf(x4[kk], wb.y, h[5]);
        h[6] = fmaf(x4[kk], wb.z, h[6]); h[7] = fmaf(x4[kk], wb.w, h[7]);
      }
    }
    *(float4*)&hs[r][c0]   = make_float4(fmaxf(h[0],0.f),fmaxf(h[1],0.f),fmaxf(h[2],0.f),fmaxf(h[3],0.f));
    *(float4*)&hs[r][c0+4] = make_float4(fmaxf(h[4],0.f),fmaxf(h[5],0.f),fmaxf(h[6],0.f),fmaxf(h[7],0.f));
  }
  __syncthreads();

  { // layer 2: 256 -> 128, 1 row x 4 cols per thread
    const int r = t >> 5, c0 = (t & 31)*4;
    float4 bb = *(const float4*)&b2[c0];
    float o[4] = {bb.x, bb.y, bb.z, bb.w};
    for(int k=0;k<256;k+=4){
      float4 xv = *(const float4*)&hs[r][k];
      float x4[4] = {xv.x, xv.y, xv.z, xv.w};
      #pragma unroll
      for(int kk=0;kk<4;kk++){
        float4 wa = *(const float4*)&W2[(size_t)(k+kk)*128 + c0];
        o[0] = fmaf(x4[kk], wa.x, o[0]); o[1] = fmaf(x4[kk], wa.y, o[1]);
        o[2] = fmaf(x4[kk], wa.z, o[2]); o[3] = fmaf(x4[kk], wa.w, o[3]);
      }
    }
    *(float4*)&Y[(size_t)(r0 + r)*128 + c0] = make_float4(o[0],o[1],o[2],o[3]);
  }
}

// ---------------------------------------------------------------- col stats
__global__ __launch_bounds__(256) void k_colstats(const float* __restrict__ C, float* __restrict__ st){
  const int t = threadIdx.x, col = t & 127, h = t >> 7;
  float s = 0.f, s2 = 0.f;
  for(int r = blockIdx.x*2 + h; r < NCL; r += 1024){   // grid = 512 blocks
    float v = C[(size_t)r*128 + col];
    s += v; s2 += v*v;
  }
  __shared__ float red[256];
  red[t] = s; __syncthreads();
  if(t < 128) atomicAdd(&st[col], red[t] + red[t+128]);
  __syncthreads();
  red[t] = s2; __syncthreads();
  if(t < 128) atomicAdd(&st[128+col], red[t] + red[t+128]);
}

__global__ void k_finstats(float* st){
  int j = threadIdx.x;
  if(j < 128){
    const float n = (float)NCL;
    float mean = st[j]/n;
    float var = (st[128+j] - n*mean*mean) / (n - 1.f);   // ddof=1
    var = fmaxf(var, 0.f);
    st[256+j] = mean;
    st[384+j] = 1.f/(sqrtf(var) + 1e-10f);
  }
}

// -------- literal side: gather(normalized on the fly) + MLP + res + LN
// 256 threads, 16 literals/block. LDS 16.5 KB -> 100% occupancy.
// Normalization is affine per column: sum_norm = (sum_raw - deg*mean)*isd.
__global__ __launch_bounds__(256) void k_lit_fused(
    const int* __restrict__ Pl, const int* __restrict__ lcl,
    const float* __restrict__ C, const float* __restrict__ st,
    const float* __restrict__ W1, const float* __restrict__ b1,
    const float* __restrict__ W2, const float* __restrict__ b2,
    const float* __restrict__ lng, const float* __restrict__ lnb, float* __restrict__ Lh){
  __shared__ float xs[16][128];
  __shared__ float hs[16][128];
  __shared__ int rng[17];
  const int t = threadIdx.x;
  const int r0 = blockIdx.x * 16;

  if(t < 17) rng[t] = (r0 + t == 0) ? 0 : Pl[r0 + t - 1];
  __syncthreads();

  { // gather: waves 0-1 rows 0..7, waves 2-3 rows 8..15
    const int f = t & 127, rr = (t >> 7)*8;
    const float mean = st[256+f], isd = st[384+f];
    for(int rs=0;rs<8;rs++){
      int r = rr + rs;
      float a = 0.f;
      int be = rng[r], en = rng[r+1];
      for(int e=be; e<en; e++) a += C[(size_t)lcl[e]*128 + f];
      xs[r][f] = (a - (float)(en-be)*mean) * isd;
    }
  }
  __syncthreads();

  const int r = t >> 4, c0 = (t & 15)*8;   // 1 row x 8 cols per thread
  float h[8];
  #pragma unroll
  for(int cc=0;cc<8;cc++) h[cc] = b1[c0+cc];
  for(int k=0;k<128;k+=4){
    float4 xv = *(const float4*)&xs[r][k];
    float x4[4] = {xv.x, xv.y, xv.z, xv.w};
    #pragma unroll
    for(int kk=0;kk<4;kk++){
      float4 wa = *(const float4*)&W1[(size_t)(k+kk)*128 + c0];
      float4 wb = *(const float4*)&W1[(size_t)(k+kk)*128 + c0 + 4];
      h[0] = fmaf(x4[kk], wa.x, h[0]); h[1] = fmaf(x4[kk], wa.y, h[1]);
      h[2] = fmaf(x4[kk], wa.z, h[2]); h[3] = fmaf(x4[kk], wa.w, h[3]);
      h[4] = fmaf(x4[kk], wb.x, h[4]); h[5] = fmaf(x4[kk], wb.y, h[5]);
      h[6] = fmaf(x4[kk], wb.z, h[6]); h[7] = fmaf(x4[kk], wb.w, h[7]);
    }
  }
  *(float4*)&hs[r][c0]   = make_float4(fmaxf(h[0],0.f),fmaxf(h[1],0.f),fmaxf(h[2],0.f),fmaxf(h[3],0.f));
  *(float4*)&hs[r][c0+4] = make_float4(fmaxf(h[4],0.f),fmaxf(h[5],0.f),fmaxf(h[6],0.f),fmaxf(h[7],0.f));
  __syncthreads();

  float y[8];
  #pragma unroll
  for(int cc=0;cc<8;cc++) y[cc] = b2[c0+cc];
  for(int k=0;k<128;k+=4){
    float4 xv = *(const float4*)&hs[r][k];
    float x4[4] = {xv.x, xv.y, xv.z, xv.w};
    #pragma unroll
    for(int kk=0;kk<4;kk++){
      float4 wa = *(const float4*)&W2[(size_t)(k+kk)*128 + c0];
      float4 wb = *(const float4*)&W2[(size_t)(k+kk)*128 + c0 + 4];
      y[0] = fmaf(x4[kk], wa.x, y[0]); y[1] = fmaf(x4[kk], wa.y, y[1]);
      y[2] = fmaf(x4[kk], wa.z, y[2]); y[3] = fmaf(x4[kk], wa.w, y[3]);
      y[4] = fmaf(x4[kk], wb.x, y[4]); y[5] = fmaf(x4[kk], wb.y, y[5]);
      y[6] = fmaf(x4[kk], wb.z, y[6]); y[7] = fmaf(x4[kk], wb.w, y[7]);
    }
  }

  { // + 0.1*residual, LayerNorm over 128 (16 lanes x 8 cols per row)
    size_t row = (size_t)(r0 + r);
    float4 la = *(const float4*)&Lh[row*128 + c0];
    float4 lc = *(const float4*)&Lh[row*128 + c0 + 4];
    y[0] += 0.1f*la.x; y[1] += 0.1f*la.y; y[2] += 0.1f*la.z; y[3] += 0.1f*la.w;
    y[4] += 0.1f*lc.x; y[5] += 0.1f*lc.y; y[6] += 0.1f*lc.z; y[7] += 0.1f*lc.w;
    float s = 0.f, s2 = 0.f;
    #pragma unroll
    for(int cc=0;cc<8;cc++){ s += y[cc]; s2 += y[cc]*y[cc]; }
    #pragma unroll
    for(int m=1;m<16;m<<=1){ s += __shfl_xor(s,m,64); s2 += __shfl_xor(s2,m,64); }
    float mean = s*(1.f/128.f);
    float var  = s2*(1.f/128.f) - mean*mean;
    float rs   = rsqrtf(fmaxf(var, 0.f) + 1e-5f);
    float o[8];
    #pragma unroll
    for(int cc=0;cc<8;cc++) o[cc] = (y[cc]-mean)*rs*lng[c0+cc] + lnb[c0+cc];
    *(float4*)&Lh[row*128 + c0]     = make_float4(o[0],o[1],o[2],o[3]);
    *(float4*)&Lh[row*128 + c0 + 4] = make_float4(o[4],o[5],o[6],o[7]);
  }
}

// ---------------------------------------------------------------- heads
// 256 threads, 8 vars/block.
__global__ __launch_bounds__(256) void k_head_v(const float* __restrict__ Lh,
    const float* __restrict__ W1d, const float* __restrict__ b1d, const float* __restrict__ W2d, const float* __restrict__ b2d,
    const float* __restrict__ W1c, const float* __restrict__ b1c, const float* __restrict__ W2c, const float* __restrict__ b2c,
    float* __restrict__ out){
  __shared__ float xs[8][256];
  const int t = threadIdx.x;
  const int v0 = blockIdx.x * 8;
  #pragma unroll
  for(int r=0;r<8;r++)
    xs[r][t] = (t < 128) ? Lh[(size_t)(v0+r)*128 + t]
                         : Lh[(size_t)(v0+r+HALFL)*128 + (t-128)];
  __syncthreads();
  const int r = t >> 5, c0 = (t & 31)*8;
  for(int hd=0; hd<2; hd++){
    const float* W1 = hd ? W1c : W1d;
    const float* b1 = hd ? b1c : b1d;
    const float* W2 = hd ? W2c : W2d;
    const float* b2 = hd ? b2c : b2d;
    float h[8];
    #pragma unroll
    for(int cc=0;cc<8;cc++) h[cc] = b1[c0+cc];
    for(int k=0;k<256;k+=4){
      float4 xv = *(const float4*)&xs[r][k];
      float x4[4] = {xv.x, xv.y, xv.z, xv.w};
      #pragma unroll
      for(int kk=0;kk<4;kk++){
        float4 wa = *(const float4*)&W1[(size_t)(k+kk)*256 + c0];
        float4 wb = *(const float4*)&W1[(size_t)(k+kk)*256 + c0 + 4];
        h[0] = fmaf(x4[kk], wa.x, h[0]); h[1] = fmaf(x4[kk], wa.y, h[1]);
        h[2] = fmaf(x4[kk], wa.z, h[2]); h[3] = fmaf(x4[kk], wa.w, h[3]);
        h[4] = fmaf(x4[kk], wb.x, h[4]); h[5] = fmaf(x4[kk], wb.y, h[5]);
        h[6] = fmaf(x4[kk], wb.z, h[6]); h[7] = fmaf(x4[kk], wb.w, h[7]);
      }
    }
    float4 w2a = *(const float4*)&W2[c0];
    float4 w2b = *(const float4*)&W2[c0+4];
    float p = fmaxf(h[0],0.f)*w2a.x + fmaxf(h[1],0.f)*w2a.y
            + fmaxf(h[2],0.f)*w2a.z + fmaxf(h[3],0.f)*w2a.w
            + fmaxf(h[4],0.f)*w2b.x + fmaxf(h[5],0.f)*w2b.y
            + fmaxf(h[6],0.f)*w2b.z + fmaxf(h[7],0.f)*w2b.w;
    #pragma unroll
    for(int m=1;m<32;m<<=1) p += __shfl_xor(p,m,64);
    if((t & 31) == 0) out[(size_t)hd*NVAR + v0 + r] = p + b2[0];
  }
}

// 256 threads, 16 clauses/block; normalizes C on load.
__global__ __launch_bounds__(256) void k_head_c(const float* __restrict__ C,
    const float* __restrict__ st,
    const float* __restrict__ W1, const float* __restrict__ b1,
    const float* __restrict__ W2, const float* __restrict__ b2,
    float* __restrict__ out){
  __shared__ float xs[16][128];
  const int t = threadIdx.x;
  const int cb = blockIdx.x * 16;
  { const int f = t & 127, rr = t >> 7;
    const float mean = st[256+f], isd = st[384+f];
    #pragma unroll
    for(int i=0;i<8;i++){
      int r = rr + i*2;
      xs[r][f] = (C[(size_t)(cb+r)*128 + f] - mean) * isd;
    }
  }
  __syncthreads();
  const int r = t >> 4, c0 = (t & 15)*8;
  float h[8];
  #pragma unroll
  for(int cc=0;cc<8;cc++) h[cc] = b1[c0+cc];
  for(int k=0;k<128;k+=4){
    float4 xv = *(const float4*)&xs[r][k];
    float x4[4] = {xv.x, xv.y, xv.z, xv.w};
    #pragma unroll
    for(int kk=0;kk<4;kk++){
      float4 wa = *(const float4*)&W1[(size_t)(k+kk)*128 + c0];
      float4 wb = *(const float4*)&W1[(size_t)(k+kk)*128 + c0 + 4];
      h[0] = fmaf(x4[kk], wa.x, h[0]); h[1] = fmaf(x4[kk], wa.y, h[1]);
      h[2] = fmaf(x4[kk], wa.z, h[2]); h[3] = fmaf(x4[kk], wa.w, h[3]);
      h[4] = fmaf(x4[kk], wb.x, h[4]); h[5] = fmaf(x4[kk], wb.y, h[5]);
      h[6] = fmaf(x4[kk], wb.z, h[6]); h[7] = fmaf(x4[kk], wb.w, h[7]);
    }
  }
  float4 w2a = *(const float4*)&W2[c0];
  float4 w2b = *(const float4*)&W2[c0+4];
  float p = fmaxf(h[0],0.f)*w2a.x + fmaxf(h[1],0.f)*w2a.y
          + fmaxf(h[2],0.f)*w2a.z + fmaxf(h[3],0.f)*w2a.w
          + fmaxf(h[4],0.f)*w2b.x + fmaxf(h[5],0.f)*w2b.y
          + fmaxf(h[6],0.f)*w2b.z + fmaxf(h[7],0.f)*w2b.w;
  #pragma unroll
  for(int m=1;m<16;m<<=1) p += __shfl_xor(p,m,64);
  if((t & 15) == 0) out[cb + r] = p + b2[0];
}

// ---------------------------------------------------------------- launch
extern "C" void kernel_launch(void* const* d_in, const int* in_sizes, int n_in,
                              void* d_out, int out_size, void* d_ws, size_t ws_size,
                              hipStream_t stream){
  const float* L0   = (const float*)d_in[0];
  const float* lng  = (const float*)d_in[1];
  const float* lnb  = (const float*)d_in[2];
  const float* CuW1 = (const float*)d_in[3];
  const float* Cub1 = (const float*)d_in[4];
  const float* CuW2 = (const float*)d_in[5];
  const float* Cub2 = (const float*)d_in[6];
  const float* LuW1 = (const float*)d_in[7];
  const float* Lub1 = (const float*)d_in[8];
  const float* LuW2 = (const float*)d_in[9];
  const float* Lub2 = (const float*)d_in[10];
  const float* VdW1 = (const float*)d_in[11];
  const float* Vdb1 = (const float*)d_in[12];
  const float* VdW2 = (const float*)d_in[13];
  const float* Vdb2 = (const float*)d_in[14];
  const float* VcW1 = (const float*)d_in[15];
  const float* Vcb1 = (const float*)d_in[16];
  const float* VcW2 = (const float*)d_in[17];
  const float* Vcb2 = (const float*)d_in[18];
  const float* CsW1 = (const float*)d_in[19];
  const float* Csb1 = (const float*)d_in[20];
  const float* CsW2 = (const float*)d_in[21];
  const float* Csb2 = (const float*)d_in[22];
  const int* cidx = (const int*)d_in[23];
  const int* lidx = (const int*)d_in[24];
  const int  ne   = in_sizes[23];

  float* ws   = (float*)d_ws;
  float* Lh   = ws;                        // 25,600,000 f32
  float* C    = ws + 25600000;             // 38,400,000 f32 -> end 64,000,000
  float* st   = ws + 64000000;             // 512: sum|sumsq|mean|isd
  int*   ib   = (int*)(ws + 64000512);     // int region
  int*   Pc   = ib;                        // PAD_C = 300,032
  int*   Pl   = ib + PAD_C;                // PAD_L = 200,704
  int*   clit = ib + PAD_C + PAD_L;        // 1,000,000
  int*   lcl  = clit + 1000000;            // 1,000,000
  int*   psum = lcl + 1000000;             // 512
  // total ws ~= 266 MB
  float* out = (float*)d_out;              // fp32: drat|core|c_core

  k_init_lh<<<100000, 256, 0, stream>>>(L0, Lh);

  // CSR build (counting sort both directions)
  k_zero4<<<489, 256, 0, stream>>>((float4*)Pc, (PAD_C + PAD_L)/4);
  k_hist<<<(ne+255)/256, 256, 0, stream>>>(cidx, lidx, Pc, Pl, ne);
  k_scan_pass1<<<NB_C, 256, 0, stream>>>(Pc, psum);
  k_scan_pass2<<<1, 512, 0, stream>>>(psum, NB_C);
  k_scan_pass3<<<NB_C, 256, 0, stream>>>(Pc, psum);
  k_scan_pass1<<<NB_L, 256, 0, stream>>>(Pl, psum);
  k_scan_pass2<<<1, 512, 0, stream>>>(psum, NB_L);
  k_scan_pass3<<<NB_L, 256, 0, stream>>>(Pl, psum);
  k_fill<<<(ne+255)/256, 256, 0, stream>>>(cidx, lidx, Pc, Pl, clit, lcl, ne);

  for(int hop=0; hop<4; hop++){
    k_zero4<<<1, 256, 0, stream>>>((float4*)st, 128);
    k_clause_fused<<<37500, 256, 0, stream>>>(Pc, clit, Lh, CuW1, Cub1, CuW2, Cub2, C);
    k_colstats<<<512, 256, 0, stream>>>(C, st);
    k_finstats<<<1, 128, 0, stream>>>(st);
    k_lit_fused<<<12500, 256, 0, stream>>>(Pl, lcl, C, st, LuW1, Lub1, LuW2, Lub2, lng, lnb, Lh);
  }
  k_head_v<<<12500, 256, 0, stream>>>(Lh, VdW1, Vdb1, VdW2, Vdb2, VcW1, Vcb1, VcW2, Vcb2, out);
  k_head_c<<<18750, 256, 0, stream>>>(C, st, CsW1, Csb1, CsW2, Csb2, out + 200000);
}

// Round 7
// 12555.138 us; speedup vs baseline: 1.4638x; 1.4638x over previous
//
#include <hip/hip_runtime.h>
#include <hip/hip_bf16.h>

#define NCL   300000
#define NLIT  200000
#define HALFL 100000
#define NVAR  100000

#define NB_C  293            // 293*1024 = 300032 >= NCL
#define PAD_C (NB_C*1024)
#define NB_L  196            // 196*1024 = 200704 >= NLIT
#define PAD_L (NB_L*1024)

// ---------------------------------------------------------------- utilities
__global__ void k_init_lh(const float* __restrict__ L0, float* __restrict__ Lh){
  int i = blockIdx.x*256 + threadIdx.x;            // 25,600,000 total
  Lh[i] = L0[i & 127];
}

__global__ void k_zero4(float4* __restrict__ p, int n4){
  int i = blockIdx.x*256 + threadIdx.x;
  if(i < n4) p[i] = make_float4(0.f,0.f,0.f,0.f);
}

// ---------------------------------------------------------------- CSR build
__global__ __launch_bounds__(256) void k_hist(const int* __restrict__ ci, const int* __restrict__ li,
    int* __restrict__ Pc, int* __restrict__ Pl, int ne){
  int e = blockIdx.x*256 + threadIdx.x;
  if(e < ne){ atomicAdd(&Pc[ci[e]], 1); atomicAdd(&Pl[li[e]], 1); }
}

__global__ __launch_bounds__(256) void k_scan_pass1(const int* __restrict__ P, int* __restrict__ psum){
  __shared__ int red[256];
  int t = threadIdx.x;
  int4 v = *(const int4*)&P[blockIdx.x*1024 + t*4];
  red[t] = v.x + v.y + v.z + v.w;
  __syncthreads();
  for(int ofs=128; ofs>0; ofs>>=1){
    if(t < ofs) red[t] += red[t+ofs];
    __syncthreads();
  }
  if(t == 0) psum[blockIdx.x] = red[0];
}

__global__ __launch_bounds__(512) void k_scan_pass2(int* __restrict__ psum, int nb){
  __shared__ int sA[512], sB[512];
  int t = threadIdx.x;
  sA[t] = (t < nb) ? psum[t] : 0;
  __syncthreads();
  int* src = sA; int* dst = sB;
  for(int ofs=1; ofs<512; ofs<<=1){
    int x = src[t];
    if(t >= ofs) x += src[t-ofs];
    dst[t] = x;
    __syncthreads();
    int* tmp = src; src = dst; dst = tmp;
  }
  psum[t] = t ? src[t-1] : 0;    // exclusive
}

__global__ __launch_bounds__(256) void k_scan_pass3(int* __restrict__ P, const int* __restrict__ psum){
  __shared__ int sA[256], sB[256];
  int t = threadIdx.x;
  int base = blockIdx.x*1024 + t*4;
  int4 v = *(const int4*)&P[base];
  int tsum = v.x + v.y + v.z + v.w;
  sA[t] = tsum;
  __syncthreads();
  int* src = sA; int* dst = sB;
  for(int ofs=1; ofs<256; ofs<<=1){
    int x = src[t];
    if(t >= ofs) x += src[t-ofs];
    dst[t] = x;
    __syncthreads();
    int* tmp = src; src = dst; dst = tmp;
  }
  int excl = psum[blockIdx.x] + src[t] - tsum;   // exclusive across whole array
  int4 o;
  o.x = excl;
  o.y = o.x + v.x;
  o.z = o.y + v.y;
  o.w = o.z + v.z;
  *(int4*)&P[base] = o;
}

// After k_fill, P[c] holds END offset of row c; begin(c) = c ? P[c-1] : 0.
__global__ __launch_bounds__(256) void k_fill(const int* __restrict__ ci, const int* __restrict__ li,
    int* __restrict__ Pc, int* __restrict__ Pl, int* __restrict__ clit, int* __restrict__ lcl, int ne){
  int e = blockIdx.x*256 + threadIdx.x;
  if(e < ne){
    int c = ci[e], l = li[e];
    clit[atomicAdd(&Pc[c], 1)] = l;
    lcl [atomicAdd(&Pl[l], 1)] = c;
  }
}

// ------------------- clause side: CSR gather + MLP 256->256->128 -> C (raw)
// 256 thr, 32 clauses/block, 4 rows x 8 cols per-thread tile.
// xs (33 KB, reused for hidden layer) -> 4 blocks/CU = 32 waves = 100% occ.
__global__ __launch_bounds__(256, 4) void k_clause_fused(
    const int* __restrict__ Pc, const int* __restrict__ clit,
    const float* __restrict__ Lh,
    const float* __restrict__ W1, const float* __restrict__ b1,
    const float* __restrict__ W2, const float* __restrict__ b2, float* __restrict__ Y){
  __shared__ float xs[32][260];
  __shared__ int rng[33];
  const int t = threadIdx.x;
  const int r0 = blockIdx.x * 32;

  if(t < 33) rng[t] = (r0 + t == 0) ? 0 : Pc[r0 + t - 1];
  __syncthreads();

  { // gather: t<128 -> direct half (feature t), t>=128 -> flipped half
    const int f = t & 127, hi = t >> 7;
    for(int r=0;r<32;r++){
      float a = 0.f;
      for(int e=rng[r]; e<rng[r+1]; e++){
        int l = clit[e];
        if(hi) l = (l < HALFL) ? l + HALFL : l - HALFL;
        a += Lh[(size_t)l*128 + f];
      }
      xs[r][(hi<<7) + f] = a;
    }
  }
  __syncthreads();

  const int rowg = t >> 5, colg = t & 31;
  const int rb = rowg * 4;
  float h[4][8];
  { // layer 1: 256 -> 256
    const int c0 = colg * 8;
    float4 ba = *(const float4*)&b1[c0];
    float4 bb = *(const float4*)&b1[c0+4];
    #pragma unroll
    for(int r=0;r<4;r++){
      h[r][0]=ba.x; h[r][1]=ba.y; h[r][2]=ba.z; h[r][3]=ba.w;
      h[r][4]=bb.x; h[r][5]=bb.y; h[r][6]=bb.z; h[r][7]=bb.w;
    }
    for(int k=0;k<256;k+=4){
      float4 xv[4];
      #pragma unroll
      for(int r=0;r<4;r++) xv[r] = *(const float4*)&xs[rb+r][k];
      #pragma unroll
      for(int kk=0;kk<4;kk++){
        float4 wa = *(const float4*)&W1[(size_t)(k+kk)*256 + c0];
        float4 wb = *(const float4*)&W1[(size_t)(k+kk)*256 + c0 + 4];
        #pragma unroll
        for(int r=0;r<4;r++){
          float x = (kk==0)?xv[r].x:(kk==1)?xv[r].y:(kk==2)?xv[r].z:xv[r].w;
          h[r][0]=fmaf(x,wa.x,h[r][0]); h[r][1]=fmaf(x,wa.y,h[r][1]);
          h[r][2]=fmaf(x,wa.z,h[r][2]); h[r][3]=fmaf(x,wa.w,h[r][3]);
          h[r][4]=fmaf(x,wb.x,h[r][4]); h[r][5]=fmaf(x,wb.y,h[r][5]);
          h[r][6]=fmaf(x,wb.z,h[r][6]); h[r][7]=fmaf(x,wb.w,h[r][7]);
        }
      }
    }
  }
  __syncthreads();               // all xs reads done -> safe to overwrite
  { const int c0 = colg * 8;
    #pragma unroll
    for(int r=0;r<4;r++){
      *(float4*)&xs[rb+r][c0]   = make_float4(fmaxf(h[r][0],0.f),fmaxf(h[r][1],0.f),fmaxf(h[r][2],0.f),fmaxf(h[r][3],0.f));
      *(float4*)&xs[rb+r][c0+4] = make_float4(fmaxf(h[r][4],0.f),fmaxf(h[r][5],0.f),fmaxf(h[r][6],0.f),fmaxf(h[r][7],0.f));
    }
  }
  __syncthreads();

  { // layer 2: 256 -> 128, 4 rows x 4 cols per thread
    const int c2 = colg * 4;
    float4 b4 = *(const float4*)&b2[c2];
    float o[4][4];
    #pragma unroll
    for(int r=0;r<4;r++){ o[r][0]=b4.x; o[r][1]=b4.y; o[r][2]=b4.z; o[r][3]=b4.w; }
    for(int k=0;k<256;k+=4){
      float4 xv[4];
      #pragma unroll
      for(int r=0;r<4;r++) xv[r] = *(const float4*)&xs[rb+r][k];
      #pragma unroll
      for(int kk=0;kk<4;kk++){
        float4 wa = *(const float4*)&W2[(size_t)(k+kk)*128 + c2];
        #pragma unroll
        for(int r=0;r<4;r++){
          float x = (kk==0)?xv[r].x:(kk==1)?xv[r].y:(kk==2)?xv[r].z:xv[r].w;
          o[r][0]=fmaf(x,wa.x,o[r][0]); o[r][1]=fmaf(x,wa.y,o[r][1]);
          o[r][2]=fmaf(x,wa.z,o[r][2]); o[r][3]=fmaf(x,wa.w,o[r][3]);
        }
      }
    }
    #pragma unroll
    for(int r=0;r<4;r++)
      *(float4*)&Y[(size_t)(r0+rb+r)*128 + c2] = make_float4(o[r][0],o[r][1],o[r][2],o[r][3]);
  }
}

// ---------------------------------------------------------------- col stats
__global__ __launch_bounds__(256) void k_colstats(const float* __restrict__ C, float* __restrict__ st){
  const int t = threadIdx.x, col = t & 127, h = t >> 7;
  float s = 0.f, s2 = 0.f;
  for(int r = blockIdx.x*2 + h; r < NCL; r += 1024){   // grid = 512 blocks
    float v = C[(size_t)r*128 + col];
    s += v; s2 += v*v;
  }
  __shared__ float red[256];
  red[t] = s; __syncthreads();
  if(t < 128) atomicAdd(&st[col], red[t] + red[t+128]);
  __syncthreads();
  red[t] = s2; __syncthreads();
  if(t < 128) atomicAdd(&st[128+col], red[t] + red[t+128]);
}

__global__ void k_finstats(float* st){
  int j = threadIdx.x;
  if(j < 128){
    const float n = (float)NCL;
    float mean = st[j]/n;
    float var = (st[128+j] - n*mean*mean) / (n - 1.f);   // ddof=1
    var = fmaxf(var, 0.f);
    st[256+j] = mean;
    st[384+j] = 1.f/(sqrtf(var) + 1e-10f);
  }
}

// -------- literal side: gather(normalized analytically) + MLP + res + LN
// 256 thr, 64 lits/block, 4 rows x 8 cols tile, xs reused -> 34 KB LDS.
__global__ __launch_bounds__(256, 4) void k_lit_fused(
    const int* __restrict__ Pl, const int* __restrict__ lcl,
    const float* __restrict__ C, const float* __restrict__ st,
    const float* __restrict__ W1, const float* __restrict__ b1,
    const float* __restrict__ W2, const float* __restrict__ b2,
    const float* __restrict__ lng, const float* __restrict__ lnb, float* __restrict__ Lh){
  __shared__ float xs[64][132];
  __shared__ int rng[65];
  const int t = threadIdx.x;
  const int r0 = blockIdx.x * 64;

  if(t < 65) rng[t] = (r0 + t == 0) ? 0 : Pl[r0 + t - 1];
  __syncthreads();

  { // gather: threads 0-127 rows 0..31, threads 128-255 rows 32..63
    const int f = t & 127, rr = (t >> 7) * 32;
    const float mean = st[256+f], isd = st[384+f];
    for(int i=0;i<32;i++){
      int r = rr + i;
      float a = 0.f;
      int be = rng[r], en = rng[r+1];
      for(int e=be; e<en; e++) a += C[(size_t)lcl[e]*128 + f];
      xs[r][f] = (a - (float)(en-be)*mean) * isd;   // column-normalized sum
    }
  }
  __syncthreads();

  const int rowg = t >> 4, colg = t & 15;
  const int rb = rowg * 4, c0 = colg * 8;
  float h[4][8];
  { // layer 1: 128 -> 128
    float4 ba = *(const float4*)&b1[c0];
    float4 bb = *(const float4*)&b1[c0+4];
    #pragma unroll
    for(int r=0;r<4;r++){
      h[r][0]=ba.x; h[r][1]=ba.y; h[r][2]=ba.z; h[r][3]=ba.w;
      h[r][4]=bb.x; h[r][5]=bb.y; h[r][6]=bb.z; h[r][7]=bb.w;
    }
    for(int k=0;k<128;k+=4){
      float4 xv[4];
      #pragma unroll
      for(int r=0;r<4;r++) xv[r] = *(const float4*)&xs[rb+r][k];
      #pragma unroll
      for(int kk=0;kk<4;kk++){
        float4 wa = *(const float4*)&W1[(size_t)(k+kk)*128 + c0];
        float4 wb = *(const float4*)&W1[(size_t)(k+kk)*128 + c0 + 4];
        #pragma unroll
        for(int r=0;r<4;r++){
          float x = (kk==0)?xv[r].x:(kk==1)?xv[r].y:(kk==2)?xv[r].z:xv[r].w;
          h[r][0]=fmaf(x,wa.x,h[r][0]); h[r][1]=fmaf(x,wa.y,h[r][1]);
          h[r][2]=fmaf(x,wa.z,h[r][2]); h[r][3]=fmaf(x,wa.w,h[r][3]);
          h[r][4]=fmaf(x,wb.x,h[r][4]); h[r][5]=fmaf(x,wb.y,h[r][5]);
          h[r][6]=fmaf(x,wb.z,h[r][6]); h[r][7]=fmaf(x,wb.w,h[r][7]);
        }
      }
    }
  }
  __syncthreads();
  #pragma unroll
  for(int r=0;r<4;r++){
    *(float4*)&xs[rb+r][c0]   = make_float4(fmaxf(h[r][0],0.f),fmaxf(h[r][1],0.f),fmaxf(h[r][2],0.f),fmaxf(h[r][3],0.f));
    *(float4*)&xs[rb+r][c0+4] = make_float4(fmaxf(h[r][4],0.f),fmaxf(h[r][5],0.f),fmaxf(h[r][6],0.f),fmaxf(h[r][7],0.f));
  }
  __syncthreads();

  float y[4][8];
  { // layer 2: 128 -> 128
    float4 ba = *(const float4*)&b2[c0];
    float4 bb = *(const float4*)&b2[c0+4];
    #pragma unroll
    for(int r=0;r<4;r++){
      y[r][0]=ba.x; y[r][1]=ba.y; y[r][2]=ba.z; y[r][3]=ba.w;
      y[r][4]=bb.x; y[r][5]=bb.y; y[r][6]=bb.z; y[r][7]=bb.w;
    }
    for(int k=0;k<128;k+=4){
      float4 xv[4];
      #pragma unroll
      for(int r=0;r<4;r++) xv[r] = *(const float4*)&xs[rb+r][k];
      #pragma unroll
      for(int kk=0;kk<4;kk++){
        float4 wa = *(const float4*)&W2[(size_t)(k+kk)*128 + c0];
        float4 wb = *(const float4*)&W2[(size_t)(k+kk)*128 + c0 + 4];
        #pragma unroll
        for(int r=0;r<4;r++){
          float x = (kk==0)?xv[r].x:(kk==1)?xv[r].y:(kk==2)?xv[r].z:xv[r].w;
          y[r][0]=fmaf(x,wa.x,y[r][0]); y[r][1]=fmaf(x,wa.y,y[r][1]);
          y[r][2]=fmaf(x,wa.z,y[r][2]); y[r][3]=fmaf(x,wa.w,y[r][3]);
          y[r][4]=fmaf(x,wb.x,y[r][4]); y[r][5]=fmaf(x,wb.y,y[r][5]);
          y[r][6]=fmaf(x,wb.z,y[r][6]); y[r][7]=fmaf(x,wb.w,y[r][7]);
        }
      }
    }
  }

  { // + 0.1*residual, LayerNorm over 128 (16 colg lanes x 8 cols)
    float4 gva = *(const float4*)&lng[c0], gvb = *(const float4*)&lng[c0+4];
    float4 bva = *(const float4*)&lnb[c0], bvb = *(const float4*)&lnb[c0+4];
    float gv[8] = {gva.x,gva.y,gva.z,gva.w, gvb.x,gvb.y,gvb.z,gvb.w};
    float bv[8] = {bva.x,bva.y,bva.z,bva.w, bvb.x,bvb.y,bvb.z,bvb.w};
    #pragma unroll
    for(int r=0;r<4;r++){
      size_t row = (size_t)(r0 + rb + r);
      float4 la = *(const float4*)&Lh[row*128 + c0];
      float4 lc = *(const float4*)&Lh[row*128 + c0 + 4];
      y[r][0] += 0.1f*la.x; y[r][1] += 0.1f*la.y; y[r][2] += 0.1f*la.z; y[r][3] += 0.1f*la.w;
      y[r][4] += 0.1f*lc.x; y[r][5] += 0.1f*lc.y; y[r][6] += 0.1f*lc.z; y[r][7] += 0.1f*lc.w;
      float s = 0.f, s2 = 0.f;
      #pragma unroll
      for(int cc=0;cc<8;cc++){ s += y[r][cc]; s2 += y[r][cc]*y[r][cc]; }
      #pragma unroll
      for(int m=1;m<16;m<<=1){ s += __shfl_xor(s,m,64); s2 += __shfl_xor(s2,m,64); }
      float mean = s*(1.f/128.f);
      float var  = s2*(1.f/128.f) - mean*mean;
      float rs   = rsqrtf(fmaxf(var, 0.f) + 1e-5f);
      float o[8];
      #pragma unroll
      for(int cc=0;cc<8;cc++) o[cc] = (y[r][cc]-mean)*rs*gv[cc] + bv[cc];
      *(float4*)&Lh[row*128 + c0]     = make_float4(o[0],o[1],o[2],o[3]);
      *(float4*)&Lh[row*128 + c0 + 4] = make_float4(o[4],o[5],o[6],o[7]);
    }
  }
}

// ---------------------------------------------------------------- heads
// 256 thr, 32 vars/block, 4x8 tile; both heads share staged xs.
__global__ __launch_bounds__(256, 4) void k_head_v(const float* __restrict__ Lh,
    const float* __restrict__ W1d, const float* __restrict__ b1d, const float* __restrict__ W2d, const float* __restrict__ b2d,
    const float* __restrict__ W1c, const float* __restrict__ b1c, const float* __restrict__ W2c, const float* __restrict__ b2c,
    float* __restrict__ out){
  __shared__ float xs[32][260];
  const int t = threadIdx.x;
  const int v0 = blockIdx.x * 32;
  { const int f = t & 127, hi = t >> 7;
    for(int r=0;r<32;r++)
      xs[r][(hi<<7)+f] = hi ? Lh[(size_t)(v0+r+HALFL)*128 + f]
                            : Lh[(size_t)(v0+r)*128 + f];
  }
  __syncthreads();
  const int rowg = t >> 5, colg = t & 31;
  const int rb = rowg*4, c0 = colg*8;
  for(int hd=0; hd<2; hd++){
    const float* W1 = hd ? W1c : W1d;
    const float* b1 = hd ? b1c : b1d;
    const float* W2 = hd ? W2c : W2d;
    const float* b2 = hd ? b2c : b2d;
    float h[4][8];
    float4 ba = *(const float4*)&b1[c0];
    float4 bb = *(const float4*)&b1[c0+4];
    #pragma unroll
    for(int r=0;r<4;r++){
      h[r][0]=ba.x; h[r][1]=ba.y; h[r][2]=ba.z; h[r][3]=ba.w;
      h[r][4]=bb.x; h[r][5]=bb.y; h[r][6]=bb.z; h[r][7]=bb.w;
    }
    for(int k=0;k<256;k+=4){
      float4 xv[4];
      #pragma unroll
      for(int r=0;r<4;r++) xv[r] = *(const float4*)&xs[rb+r][k];
      #pragma unroll
      for(int kk=0;kk<4;kk++){
        float4 wa = *(const float4*)&W1[(size_t)(k+kk)*256 + c0];
        float4 wb = *(const float4*)&W1[(size_t)(k+kk)*256 + c0 + 4];
        #pragma unroll
        for(int r=0;r<4;r++){
          float x = (kk==0)?xv[r].x:(kk==1)?xv[r].y:(kk==2)?xv[r].z:xv[r].w;
          h[r][0]=fmaf(x,wa.x,h[r][0]); h[r][1]=fmaf(x,wa.y,h[r][1]);
          h[r][2]=fmaf(x,wa.z,h[r][2]); h[r][3]=fmaf(x,wa.w,h[r][3]);
          h[r][4]=fmaf(x,wb.x,h[r][4]); h[r][5]=fmaf(x,wb.y,h[r][5]);
          h[r][6]=fmaf(x,wb.z,h[r][6]); h[r][7]=fmaf(x,wb.w,h[r][7]);
        }
      }
    }
    float4 w2a = *(const float4*)&W2[c0];
    float4 w2b = *(const float4*)&W2[c0+4];
    #pragma unroll
    for(int r=0;r<4;r++){
      float p = fmaxf(h[r][0],0.f)*w2a.x + fmaxf(h[r][1],0.f)*w2a.y
              + fmaxf(h[r][2],0.f)*w2a.z + fmaxf(h[r][3],0.f)*w2a.w
              + fmaxf(h[r][4],0.f)*w2b.x + fmaxf(h[r][5],0.f)*w2b.y
              + fmaxf(h[r][6],0.f)*w2b.z + fmaxf(h[r][7],0.f)*w2b.w;
      #pragma unroll
      for(int m=1;m<32;m<<=1) p += __shfl_xor(p,m,64);
      if(colg == 0) out[(size_t)hd*NVAR + v0 + rb + r] = p + b2[0];
    }
  }
}

// 256 thr, 32 clauses/block, 4x4 tile; normalizes C on load.
__global__ __launch_bounds__(256, 4) void k_head_c(const float* __restrict__ C,
    const float* __restrict__ st,
    const float* __restrict__ W1, const float* __restrict__ b1,
    const float* __restrict__ W2, const float* __restrict__ b2,
    float* __restrict__ out){
  __shared__ float xs[32][132];
  const int t = threadIdx.x;
  const int cb = blockIdx.x * 32;
  { const int f = t & 127, rr = (t >> 7)*16;
    const float mean = st[256+f], isd = st[384+f];
    for(int i=0;i<16;i++){
      int r = rr + i;
      xs[r][f] = (C[(size_t)(cb+r)*128 + f] - mean) * isd;
    }
  }
  __syncthreads();
  const int rowg = t >> 5, colg = t & 31;
  const int rb = rowg*4, c0 = colg*4;
  float h[4][4];
  float4 b4 = *(const float4*)&b1[c0];
  #pragma unroll
  for(int r=0;r<4;r++){ h[r][0]=b4.x; h[r][1]=b4.y; h[r][2]=b4.z; h[r][3]=b4.w; }
  for(int k=0;k<128;k+=4){
    float4 xv[4];
    #pragma unroll
    for(int r=0;r<4;r++) xv[r] = *(const float4*)&xs[rb+r][k];
    #pragma unroll
    for(int kk=0;kk<4;kk++){
      float4 wa = *(const float4*)&W1[(size_t)(k+kk)*128 + c0];
      #pragma unroll
      for(int r=0;r<4;r++){
        float x = (kk==0)?xv[r].x:(kk==1)?xv[r].y:(kk==2)?xv[r].z:xv[r].w;
        h[r][0]=fmaf(x,wa.x,h[r][0]); h[r][1]=fmaf(x,wa.y,h[r][1]);
        h[r][2]=fmaf(x,wa.z,h[r][2]); h[r][3]=fmaf(x,wa.w,h[r][3]);
      }
    }
  }
  float4 w2 = *(const float4*)&W2[c0];
  #pragma unroll
  for(int r=0;r<4;r++){
    float p = fmaxf(h[r][0],0.f)*w2.x + fmaxf(h[r][1],0.f)*w2.y
            + fmaxf(h[r][2],0.f)*w2.z + fmaxf(h[r][3],0.f)*w2.w;
    #pragma unroll
    for(int m=1;m<32;m<<=1) p += __shfl_xor(p,m,64);
    if(colg == 0) out[cb + rb + r] = p + b2[0];
  }
}

// ---------------------------------------------------------------- launch
extern "C" void kernel_launch(void* const* d_in, const int* in_sizes, int n_in,
                              void* d_out, int out_size, void* d_ws, size_t ws_size,
                              hipStream_t stream){
  const float* L0   = (const float*)d_in[0];
  const float* lng  = (const float*)d_in[1];
  const float* lnb  = (const float*)d_in[2];
  const float* CuW1 = (const float*)d_in[3];
  const float* Cub1 = (const float*)d_in[4];
  const float* CuW2 = (const float*)d_in[5];
  const float* Cub2 = (const float*)d_in[6];
  const float* LuW1 = (const float*)d_in[7];
  const float* Lub1 = (const float*)d_in[8];
  const float* LuW2 = (const float*)d_in[9];
  const float* Lub2 = (const float*)d_in[10];
  const float* VdW1 = (const float*)d_in[11];
  const float* Vdb1 = (const float*)d_in[12];
  const float* VdW2 = (const float*)d_in[13];
  const float* Vdb2 = (const float*)d_in[14];
  const float* VcW1 = (const float*)d_in[15];
  const float* Vcb1 = (const float*)d_in[16];
  const float* VcW2 = (const float*)d_in[17];
  const float* Vcb2 = (const float*)d_in[18];
  const float* CsW1 = (const float*)d_in[19];
  const float* Csb1 = (const float*)d_in[20];
  const float* CsW2 = (const float*)d_in[21];
  const float* Csb2 = (const float*)d_in[22];
  const int* cidx = (const int*)d_in[23];
  const int* lidx = (const int*)d_in[24];
  const int  ne   = in_sizes[23];

  float* ws   = (float*)d_ws;
  float* Lh   = ws;                        // 25,600,000 f32
  float* C    = ws + 25600000;             // 38,400,000 f32 -> end 64,000,000
  float* st   = ws + 64000000;             // 512: sum|sumsq|mean|isd
  int*   ib   = (int*)(ws + 64000512);     // int region
  int*   Pc   = ib;                        // PAD_C = 300,032
  int*   Pl   = ib + PAD_C;                // PAD_L = 200,704
  int*   clit = ib + PAD_C + PAD_L;        // 1,000,000
  int*   lcl  = clit + 1000000;            // 1,000,000
  int*   psum = lcl + 1000000;             // 512
  // total ws ~= 266 MB
  float* out = (float*)d_out;              // fp32: drat|core|c_core

  k_init_lh<<<100000, 256, 0, stream>>>(L0, Lh);

  // CSR build (counting sort both directions)
  k_zero4<<<489, 256, 0, stream>>>((float4*)Pc, (PAD_C + PAD_L)/4);
  k_hist<<<(ne+255)/256, 256, 0, stream>>>(cidx, lidx, Pc, Pl, ne);
  k_scan_pass1<<<NB_C, 256, 0, stream>>>(Pc, psum);
  k_scan_pass2<<<1, 512, 0, stream>>>(psum, NB_C);
  k_scan_pass3<<<NB_C, 256, 0, stream>>>(Pc, psum);
  k_scan_pass1<<<NB_L, 256, 0, stream>>>(Pl, psum);
  k_scan_pass2<<<1, 512, 0, stream>>>(psum, NB_L);
  k_scan_pass3<<<NB_L, 256, 0, stream>>>(Pl, psum);
  k_fill<<<(ne+255)/256, 256, 0, stream>>>(cidx, lidx, Pc, Pl, clit, lcl, ne);

  for(int hop=0; hop<4; hop++){
    k_zero4<<<1, 256, 0, stream>>>((float4*)st, 128);
    k_clause_fused<<<9375, 256, 0, stream>>>(Pc, clit, Lh, CuW1, Cub1, CuW2, Cub2, C);
    k_colstats<<<512, 256, 0, stream>>>(C, st);
    k_finstats<<<1, 128, 0, stream>>>(st);
    k_lit_fused<<<3125, 256, 0, stream>>>(Pl, lcl, C, st, LuW1, Lub1, LuW2, Lub2, lng, lnb, Lh);
  }
  k_head_v<<<3125, 256, 0, stream>>>(Lh, VdW1, Vdb1, VdW2, Vdb2, VcW1, Vcb1, VcW2, Vcb2, out);
  k_head_c<<<9375, 256, 0, stream>>>(C, st, CsW1, Csb1, CsW2, Csb2, out + 200000);
}

// Round 8
// 7363.460 us; speedup vs baseline: 2.4958x; 1.7051x over previous
//
#include <hip/hip_runtime.h>
#include <hip/hip_bf16.h>

#define NCL   300000
#define NLIT  200000
#define HALFL 100000
#define NVAR  100000

#define NB_C  293            // 293*1024 = 300032 >= NCL
#define PAD_C (NB_C*1024)
#define NB_L  196            // 196*1024 = 200704 >= NLIT
#define PAD_L (NB_L*1024)

// ---------------------------------------------------------------- utilities
__global__ void k_init_lh(const float* __restrict__ L0, float* __restrict__ Lh){
  int i = blockIdx.x*256 + threadIdx.x;            // 25,600,000 total
  Lh[i] = L0[i & 127];
}

__global__ void k_zero4(float4* __restrict__ p, int n4){
  int i = blockIdx.x*256 + threadIdx.x;
  if(i < n4) p[i] = make_float4(0.f,0.f,0.f,0.f);
}

// ---------------------------------------------------------------- CSR build
__global__ __launch_bounds__(256) void k_hist(const int* __restrict__ ci, const int* __restrict__ li,
    int* __restrict__ Pc, int* __restrict__ Pl, int ne){
  int e = blockIdx.x*256 + threadIdx.x;
  if(e < ne){ atomicAdd(&Pc[ci[e]], 1); atomicAdd(&Pl[li[e]], 1); }
}

__global__ __launch_bounds__(256) void k_scan_pass1(const int* __restrict__ P, int* __restrict__ psum){
  __shared__ int red[256];
  int t = threadIdx.x;
  int4 v = *(const int4*)&P[blockIdx.x*1024 + t*4];
  red[t] = v.x + v.y + v.z + v.w;
  __syncthreads();
  for(int ofs=128; ofs>0; ofs>>=1){
    if(t < ofs) red[t] += red[t+ofs];
    __syncthreads();
  }
  if(t == 0) psum[blockIdx.x] = red[0];
}

__global__ __launch_bounds__(512) void k_scan_pass2(int* __restrict__ psum, int nb){
  __shared__ int sA[512], sB[512];
  int t = threadIdx.x;
  sA[t] = (t < nb) ? psum[t] : 0;
  __syncthreads();
  int* src = sA; int* dst = sB;
  for(int ofs=1; ofs<512; ofs<<=1){
    int x = src[t];
    if(t >= ofs) x += src[t-ofs];
    dst[t] = x;
    __syncthreads();
    int* tmp = src; src = dst; dst = tmp;
  }
  psum[t] = t ? src[t-1] : 0;    // exclusive
}

__global__ __launch_bounds__(256) void k_scan_pass3(int* __restrict__ P, const int* __restrict__ psum){
  __shared__ int sA[256], sB[256];
  int t = threadIdx.x;
  int base = blockIdx.x*1024 + t*4;
  int4 v = *(const int4*)&P[base];
  int tsum = v.x + v.y + v.z + v.w;
  sA[t] = tsum;
  __syncthreads();
  int* src = sA; int* dst = sB;
  for(int ofs=1; ofs<256; ofs<<=1){
    int x = src[t];
    if(t >= ofs) x += src[t-ofs];
    dst[t] = x;
    __syncthreads();
    int* tmp = src; src = dst; dst = tmp;
  }
  int excl = psum[blockIdx.x] + src[t] - tsum;   // exclusive across whole array
  int4 o;
  o.x = excl;
  o.y = o.x + v.x;
  o.z = o.y + v.y;
  o.w = o.z + v.z;
  *(int4*)&P[base] = o;
}

// After k_fill, P[c] holds END offset of row c; begin(c) = c ? P[c-1] : 0.
__global__ __launch_bounds__(256) void k_fill(const int* __restrict__ ci, const int* __restrict__ li,
    int* __restrict__ Pc, int* __restrict__ Pl, int* __restrict__ clit, int* __restrict__ lcl, int ne){
  int e = blockIdx.x*256 + threadIdx.x;
  if(e < ne){
    int c = ci[e], l = li[e];
    clit[atomicAdd(&Pc[c], 1)] = l;
    lcl [atomicAdd(&Pl[l], 1)] = c;
  }
}

// ------------------- clause side: CSR gather + MLP 256->256->128 -> C (raw)
// 64 thr (1 wave), 8 clauses/block. xs reused for hidden -> 8.4 KB LDS
// -> ~16 waves/CU (VGPR-capped). float4 pipelined gather.
__global__ __launch_bounds__(64) void k_clause_fused(
    const int* __restrict__ Pc, const int* __restrict__ clit,
    const float* __restrict__ Lh,
    const float* __restrict__ W1, const float* __restrict__ b1,
    const float* __restrict__ W2, const float* __restrict__ b2, float* __restrict__ Y){
  __shared__ float xs[8][260];
  __shared__ int rng[9];
  const int t = threadIdx.x;
  const int r0 = blockIdx.x * 8;

  if(t < 9) rng[t] = (r0 + t == 0) ? 0 : Pc[r0 + t - 1];
  __syncthreads();

  { // gather: lanes 0-31 direct half, lanes 32-63 flipped half; float4/lane/edge
    const int half = t >> 5, f4 = (t & 31) * 4;
    for(int r=0;r<8;r++){
      int be = rng[r], en = rng[r+1];
      float4 a = make_float4(0.f,0.f,0.f,0.f);
      int l = (be < en) ? clit[be] : 0;
      for(int e=be; e<en; e++){
        int lnext = (e+1 < en) ? clit[e+1] : 0;          // prefetch next index
        int src = half ? ((l < HALFL) ? l + HALFL : l - HALFL) : l;
        float4 v = *(const float4*)&Lh[(size_t)src*128 + f4];
        a.x += v.x; a.y += v.y; a.z += v.z; a.w += v.w;
        l = lnext;
      }
      *(float4*)&xs[r][(half<<7) + f4] = a;
    }
  }
  __syncthreads();

  float h[4][8];
  { // layer 1: 256->256, 4 rows x 8 cols per thread
    const int c0 = (t & 31)*8, rb = (t >> 5)*4;
    #pragma unroll
    for(int cc=0;cc<8;cc++){
      float bv = b1[c0+cc];
      #pragma unroll
      for(int r=0;r<4;r++) h[r][cc]=bv;
    }
    for(int k=0;k<256;k+=4){
      float4 xv[4];
      #pragma unroll
      for(int r=0;r<4;r++) xv[r] = *(const float4*)&xs[rb+r][k];
      #pragma unroll
      for(int kk=0;kk<4;kk++){
        float4 wa = *(const float4*)&W1[(size_t)(k+kk)*256 + c0];
        float4 wb = *(const float4*)&W1[(size_t)(k+kk)*256 + c0 + 4];
        #pragma unroll
        for(int r=0;r<4;r++){
          float x = (kk==0)?xv[r].x:(kk==1)?xv[r].y:(kk==2)?xv[r].z:xv[r].w;
          h[r][0]=fmaf(x,wa.x,h[r][0]); h[r][1]=fmaf(x,wa.y,h[r][1]);
          h[r][2]=fmaf(x,wa.z,h[r][2]); h[r][3]=fmaf(x,wa.w,h[r][3]);
          h[r][4]=fmaf(x,wb.x,h[r][4]); h[r][5]=fmaf(x,wb.y,h[r][5]);
          h[r][6]=fmaf(x,wb.z,h[r][6]); h[r][7]=fmaf(x,wb.w,h[r][7]);
        }
      }
    }
  }
  __syncthreads();               // xs reads complete -> safe to overwrite
  { const int c0 = (t & 31)*8, rb = (t >> 5)*4;
    #pragma unroll
    for(int r=0;r<4;r++){
      *(float4*)&xs[rb+r][c0]   = make_float4(fmaxf(h[r][0],0.f),fmaxf(h[r][1],0.f),fmaxf(h[r][2],0.f),fmaxf(h[r][3],0.f));
      *(float4*)&xs[rb+r][c0+4] = make_float4(fmaxf(h[r][4],0.f),fmaxf(h[r][5],0.f),fmaxf(h[r][6],0.f),fmaxf(h[r][7],0.f));
    }
  }
  __syncthreads();

  { // layer 2: 256 -> 128, 2 rows x 8 cols per thread
    const int c0 = (t & 15)*8, rb = (t >> 4)*2;
    float o[2][8];
    #pragma unroll
    for(int cc=0;cc<8;cc++){ float bv = b2[c0+cc]; o[0][cc]=bv; o[1][cc]=bv; }
    for(int k=0;k<256;k+=4){
      float4 xv[2];
      #pragma unroll
      for(int r=0;r<2;r++) xv[r] = *(const float4*)&xs[rb+r][k];
      #pragma unroll
      for(int kk=0;kk<4;kk++){
        float4 wa = *(const float4*)&W2[(size_t)(k+kk)*128 + c0];
        float4 wb = *(const float4*)&W2[(size_t)(k+kk)*128 + c0 + 4];
        #pragma unroll
        for(int r=0;r<2;r++){
          float x = (kk==0)?xv[r].x:(kk==1)?xv[r].y:(kk==2)?xv[r].z:xv[r].w;
          o[r][0]=fmaf(x,wa.x,o[r][0]); o[r][1]=fmaf(x,wa.y,o[r][1]);
          o[r][2]=fmaf(x,wa.z,o[r][2]); o[r][3]=fmaf(x,wa.w,o[r][3]);
          o[r][4]=fmaf(x,wb.x,o[r][4]); o[r][5]=fmaf(x,wb.y,o[r][5]);
          o[r][6]=fmaf(x,wb.z,o[r][6]); o[r][7]=fmaf(x,wb.w,o[r][7]);
        }
      }
    }
    #pragma unroll
    for(int r=0;r<2;r++){
      *(float4*)&Y[(size_t)(r0+rb+r)*128 + c0]     = make_float4(o[r][0],o[r][1],o[r][2],o[r][3]);
      *(float4*)&Y[(size_t)(r0+rb+r)*128 + c0 + 4] = make_float4(o[r][4],o[r][5],o[r][6],o[r][7]);
    }
  }
}

// ---------------------------------------------------------------- col stats
__global__ __launch_bounds__(256) void k_colstats(const float* __restrict__ C, float* __restrict__ st){
  const int t = threadIdx.x, col = t & 127, h = t >> 7;
  float s = 0.f, s2 = 0.f;
  for(int r = blockIdx.x*2 + h; r < NCL; r += 1024){   // grid = 512 blocks
    float v = C[(size_t)r*128 + col];
    s += v; s2 += v*v;
  }
  __shared__ float red[256];
  red[t] = s; __syncthreads();
  if(t < 128) atomicAdd(&st[col], red[t] + red[t+128]);
  __syncthreads();
  red[t] = s2; __syncthreads();
  if(t < 128) atomicAdd(&st[128+col], red[t] + red[t+128]);
}

__global__ void k_finstats(float* st){
  int j = threadIdx.x;
  if(j < 128){
    const float n = (float)NCL;
    float mean = st[j]/n;
    float var = (st[128+j] - n*mean*mean) / (n - 1.f);   // ddof=1
    var = fmaxf(var, 0.f);
    st[256+j] = mean;
    st[384+j] = 1.f/(sqrtf(var) + 1e-10f);
  }
}

// -------- literal side: gather (analytically normalized) + MLP + res + LN
// 64 thr, 8 literals/block. xs reused -> 4.3 KB LDS. float4 pipelined gather,
// two row-streams (lanes 0-31 rows 0-3, lanes 32-63 rows 4-7).
__global__ __launch_bounds__(64) void k_lit_fused(
    const int* __restrict__ Pl, const int* __restrict__ lcl,
    const float* __restrict__ C, const float* __restrict__ st,
    const float* __restrict__ W1, const float* __restrict__ b1,
    const float* __restrict__ W2, const float* __restrict__ b2,
    const float* __restrict__ lng, const float* __restrict__ lnb, float* __restrict__ Lh){
  __shared__ float xs[8][132];
  __shared__ int rng[9];
  const int t = threadIdx.x;
  const int r0 = blockIdx.x * 8;

  if(t < 9) rng[t] = (r0 + t == 0) ? 0 : Pl[r0 + t - 1];
  __syncthreads();

  { const int half = t >> 5, f4 = (t & 31) * 4;
    float4 mean4 = *(const float4*)&st[256+f4];
    float4 isd4  = *(const float4*)&st[384+f4];
    for(int i=0;i<4;i++){
      int r = half*4 + i;
      int be = rng[r], en = rng[r+1];
      float4 a = make_float4(0.f,0.f,0.f,0.f);
      int c = (be < en) ? lcl[be] : 0;
      for(int e=be; e<en; e++){
        int cnext = (e+1 < en) ? lcl[e+1] : 0;
        float4 v = *(const float4*)&C[(size_t)c*128 + f4];
        a.x += v.x; a.y += v.y; a.z += v.z; a.w += v.w;
        c = cnext;
      }
      float dg = (float)(en - be);
      a.x = (a.x - dg*mean4.x)*isd4.x; a.y = (a.y - dg*mean4.y)*isd4.y;
      a.z = (a.z - dg*mean4.z)*isd4.z; a.w = (a.w - dg*mean4.w)*isd4.w;
      *(float4*)&xs[r][f4] = a;
    }
  }
  __syncthreads();

  const int c0 = (t & 15)*8, rb = (t >> 4)*2;
  float h[2][8];
  #pragma unroll
  for(int cc=0;cc<8;cc++){ float bv = b1[c0+cc]; h[0][cc]=bv; h[1][cc]=bv; }
  for(int k=0;k<128;k+=4){
    float4 xv[2];
    #pragma unroll
    for(int r=0;r<2;r++) xv[r] = *(const float4*)&xs[rb+r][k];
    #pragma unroll
    for(int kk=0;kk<4;kk++){
      float4 wa = *(const float4*)&W1[(size_t)(k+kk)*128 + c0];
      float4 wb = *(const float4*)&W1[(size_t)(k+kk)*128 + c0 + 4];
      #pragma unroll
      for(int r=0;r<2;r++){
        float x = (kk==0)?xv[r].x:(kk==1)?xv[r].y:(kk==2)?xv[r].z:xv[r].w;
        h[r][0]=fmaf(x,wa.x,h[r][0]); h[r][1]=fmaf(x,wa.y,h[r][1]);
        h[r][2]=fmaf(x,wa.z,h[r][2]); h[r][3]=fmaf(x,wa.w,h[r][3]);
        h[r][4]=fmaf(x,wb.x,h[r][4]); h[r][5]=fmaf(x,wb.y,h[r][5]);
        h[r][6]=fmaf(x,wb.z,h[r][6]); h[r][7]=fmaf(x,wb.w,h[r][7]);
      }
    }
  }
  __syncthreads();
  #pragma unroll
  for(int r=0;r<2;r++){
    *(float4*)&xs[rb+r][c0]   = make_float4(fmaxf(h[r][0],0.f),fmaxf(h[r][1],0.f),fmaxf(h[r][2],0.f),fmaxf(h[r][3],0.f));
    *(float4*)&xs[rb+r][c0+4] = make_float4(fmaxf(h[r][4],0.f),fmaxf(h[r][5],0.f),fmaxf(h[r][6],0.f),fmaxf(h[r][7],0.f));
  }
  __syncthreads();

  float y[2][8];
  #pragma unroll
  for(int cc=0;cc<8;cc++){ float bv = b2[c0+cc]; y[0][cc]=bv; y[1][cc]=bv; }
  for(int k=0;k<128;k+=4){
    float4 xv[2];
    #pragma unroll
    for(int r=0;r<2;r++) xv[r] = *(const float4*)&xs[rb+r][k];
    #pragma unroll
    for(int kk=0;kk<4;kk++){
      float4 wa = *(const float4*)&W2[(size_t)(k+kk)*128 + c0];
      float4 wb = *(const float4*)&W2[(size_t)(k+kk)*128 + c0 + 4];
      #pragma unroll
      for(int r=0;r<2;r++){
        float x = (kk==0)?xv[r].x:(kk==1)?xv[r].y:(kk==2)?xv[r].z:xv[r].w;
        y[r][0]=fmaf(x,wa.x,y[r][0]); y[r][1]=fmaf(x,wa.y,y[r][1]);
        y[r][2]=fmaf(x,wa.z,y[r][2]); y[r][3]=fmaf(x,wa.w,y[r][3]);
        y[r][4]=fmaf(x,wb.x,y[r][4]); y[r][5]=fmaf(x,wb.y,y[r][5]);
        y[r][6]=fmaf(x,wb.z,y[r][6]); y[r][7]=fmaf(x,wb.w,y[r][7]);
      }
    }
  }

  float gv[8], bv[8];
  #pragma unroll
  for(int cc=0;cc<8;cc++){ gv[cc]=lng[c0+cc]; bv[cc]=lnb[c0+cc]; }
  #pragma unroll
  for(int r=0;r<2;r++){
    size_t row = (size_t)(r0 + rb + r);
    float4 la = *(const float4*)&Lh[row*128 + c0];
    float4 lc = *(const float4*)&Lh[row*128 + c0 + 4];
    y[r][0] += 0.1f*la.x; y[r][1] += 0.1f*la.y; y[r][2] += 0.1f*la.z; y[r][3] += 0.1f*la.w;
    y[r][4] += 0.1f*lc.x; y[r][5] += 0.1f*lc.y; y[r][6] += 0.1f*lc.z; y[r][7] += 0.1f*lc.w;
    float s = 0.f, s2 = 0.f;
    #pragma unroll
    for(int cc=0;cc<8;cc++){ s += y[r][cc]; s2 += y[r][cc]*y[r][cc]; }
    #pragma unroll
    for(int m=1;m<16;m<<=1){ s += __shfl_xor(s,m,64); s2 += __shfl_xor(s2,m,64); }
    float mean = s*(1.f/128.f);
    float var  = s2*(1.f/128.f) - mean*mean;
    float rs   = rsqrtf(fmaxf(var, 0.f) + 1e-5f);
    float o[8];
    #pragma unroll
    for(int cc=0;cc<8;cc++) o[cc] = (y[r][cc]-mean)*rs*gv[cc] + bv[cc];
    *(float4*)&Lh[row*128 + c0]     = make_float4(o[0],o[1],o[2],o[3]);
    *(float4*)&Lh[row*128 + c0 + 4] = make_float4(o[4],o[5],o[6],o[7]);
  }
}

// ---------------------------------------------------------------- heads
__global__ __launch_bounds__(64) void k_head_v(const float* __restrict__ Lh,
    const float* __restrict__ W1d, const float* __restrict__ b1d, const float* __restrict__ W2d, const float* __restrict__ b2d,
    const float* __restrict__ W1c, const float* __restrict__ b1c, const float* __restrict__ W2c, const float* __restrict__ b2c,
    float* __restrict__ out){
  __shared__ float xs[8][256];
  const int t = threadIdx.x;
  const size_t v0 = (size_t)blockIdx.x * 8;
  #pragma unroll
  for(int r=0;r<8;r++){
    xs[r][t]     = Lh[(v0+r)*128 + t];
    xs[r][t+64]  = Lh[(v0+r)*128 + t + 64];
    xs[r][t+128] = Lh[(v0+r+HALFL)*128 + t];
    xs[r][t+192] = Lh[(v0+r+HALFL)*128 + t + 64];
  }
  __syncthreads();
  for(int hd=0; hd<2; hd++){
    const float* W1 = hd ? W1c : W1d;
    const float* b1 = hd ? b1c : b1d;
    const float* W2 = hd ? W2c : W2d;
    const float* b2 = hd ? b2c : b2d;
    float acc[8][4];
    #pragma unroll
    for(int c=0;c<4;c++){
      float bvv = b1[t + 64*c];
      #pragma unroll
      for(int r=0;r<8;r++) acc[r][c]=bvv;
    }
    for(int k=0;k<256;k+=4){
      float w[4][4];
      #pragma unroll
      for(int kk=0;kk<4;kk++)
        #pragma unroll
        for(int c=0;c<4;c++) w[kk][c] = W1[(size_t)(k+kk)*256 + t + 64*c];
      #pragma unroll
      for(int r=0;r<8;r++){
        float4 tv = *(const float4*)&xs[r][k];
        #pragma unroll
        for(int c=0;c<4;c++)
          acc[r][c] += tv.x*w[0][c] + tv.y*w[1][c] + tv.z*w[2][c] + tv.w*w[3][c];
      }
    }
    float w2[4];
    #pragma unroll
    for(int c=0;c<4;c++) w2[c] = W2[t + 64*c];
    float bb = b2[0];
    #pragma unroll
    for(int r=0;r<8;r++){
      float o = fmaxf(acc[r][0],0.f)*w2[0] + fmaxf(acc[r][1],0.f)*w2[1]
              + fmaxf(acc[r][2],0.f)*w2[2] + fmaxf(acc[r][3],0.f)*w2[3];
      #pragma unroll
      for(int m=1;m<64;m<<=1) o += __shfl_xor(o,m,64);
      if(t == 0) out[(size_t)hd*NVAR + v0 + r] = o + bb;
    }
  }
}

// 64 thr, 8 clauses/block; normalizes C on load.
__global__ __launch_bounds__(64) void k_head_c(const float* __restrict__ C,
    const float* __restrict__ st,
    const float* __restrict__ W1, const float* __restrict__ b1,
    const float* __restrict__ W2, const float* __restrict__ b2,
    float* __restrict__ out){
  __shared__ float xs[8][128];
  const int t = threadIdx.x;
  const size_t c0 = (size_t)blockIdx.x * 8;
  { float m0 = st[256+t], m1 = st[256+t+64];
    float i0 = st[384+t], i1 = st[384+t+64];
    #pragma unroll
    for(int r=0;r<8;r++){
      xs[r][t]    = (C[(c0+r)*128 + t]      - m0) * i0;
      xs[r][t+64] = (C[(c0+r)*128 + t + 64] - m1) * i1;
    }
  }
  __syncthreads();
  float a0[8], a1[8];
  float bv0 = b1[t], bv1 = b1[t+64];
  #pragma unroll
  for(int r=0;r<8;r++){ a0[r]=bv0; a1[r]=bv1; }
  for(int k=0;k<128;k+=4){
    float w0[4], w1[4];
    #pragma unroll
    for(int kk=0;kk<4;kk++){ w0[kk]=W1[(size_t)(k+kk)*128 + t]; w1[kk]=W1[(size_t)(k+kk)*128 + t + 64]; }
    #pragma unroll
    for(int r=0;r<8;r++){
      float4 tv = *(const float4*)&xs[r][k];
      a0[r] += tv.x*w0[0]+tv.y*w0[1]+tv.z*w0[2]+tv.w*w0[3];
      a1[r] += tv.x*w1[0]+tv.y*w1[1]+tv.z*w1[2]+tv.w*w1[3];
    }
  }
  float w2a = W2[t], w2b = W2[t+64];
  float bb = b2[0];
  #pragma unroll
  for(int r=0;r<8;r++){
    float o = fmaxf(a0[r],0.f)*w2a + fmaxf(a1[r],0.f)*w2b;
    #pragma unroll
    for(int m=1;m<64;m<<=1) o += __shfl_xor(o,m,64);
    if(t == 0) out[c0 + r] = o + bb;
  }
}

// ---------------------------------------------------------------- launch
extern "C" void kernel_launch(void* const* d_in, const int* in_sizes, int n_in,
                              void* d_out, int out_size, void* d_ws, size_t ws_size,
                              hipStream_t stream){
  const float* L0   = (const float*)d_in[0];
  const float* lng  = (const float*)d_in[1];
  const float* lnb  = (const float*)d_in[2];
  const float* CuW1 = (const float*)d_in[3];
  const float* Cub1 = (const float*)d_in[4];
  const float* CuW2 = (const float*)d_in[5];
  const float* Cub2 = (const float*)d_in[6];
  const float* LuW1 = (const float*)d_in[7];
  const float* Lub1 = (const float*)d_in[8];
  const float* LuW2 = (const float*)d_in[9];
  const float* Lub2 = (const float*)d_in[10];
  const float* VdW1 = (const float*)d_in[11];
  const float* Vdb1 = (const float*)d_in[12];
  const float* VdW2 = (const float*)d_in[13];
  const float* Vdb2 = (const float*)d_in[14];
  const float* VcW1 = (const float*)d_in[15];
  const float* Vcb1 = (const float*)d_in[16];
  const float* VcW2 = (const float*)d_in[17];
  const float* Vcb2 = (const float*)d_in[18];
  const float* CsW1 = (const float*)d_in[19];
  const float* Csb1 = (const float*)d_in[20];
  const float* CsW2 = (const float*)d_in[21];
  const float* Csb2 = (const float*)d_in[22];
  const int* cidx = (const int*)d_in[23];
  const int* lidx = (const int*)d_in[24];
  const int  ne   = in_sizes[23];

  float* ws   = (float*)d_ws;
  float* Lh   = ws;                        // 25,600,000 f32
  float* C    = ws + 25600000;             // 38,400,000 f32 -> end 64,000,000
  float* st   = ws + 64000000;             // 512: sum|sumsq|mean|isd
  int*   ib   = (int*)(ws + 64000512);     // int region
  int*   Pc   = ib;                        // PAD_C = 300,032
  int*   Pl   = ib + PAD_C;                // PAD_L = 200,704
  int*   clit = ib + PAD_C + PAD_L;        // 1,000,000
  int*   lcl  = clit + 1000000;            // 1,000,000
  int*   psum = lcl + 1000000;             // 512
  // total ws ~= 266 MB
  float* out = (float*)d_out;              // fp32: drat|core|c_core

  k_init_lh<<<100000, 256, 0, stream>>>(L0, Lh);

  // CSR build (counting sort both directions)
  k_zero4<<<489, 256, 0, stream>>>((float4*)Pc, (PAD_C + PAD_L)/4);
  k_hist<<<(ne+255)/256, 256, 0, stream>>>(cidx, lidx, Pc, Pl, ne);
  k_scan_pass1<<<NB_C, 256, 0, stream>>>(Pc, psum);
  k_scan_pass2<<<1, 512, 0, stream>>>(psum, NB_C);
  k_scan_pass3<<<NB_C, 256, 0, stream>>>(Pc, psum);
  k_scan_pass1<<<NB_L, 256, 0, stream>>>(Pl, psum);
  k_scan_pass2<<<1, 512, 0, stream>>>(psum, NB_L);
  k_scan_pass3<<<NB_L, 256, 0, stream>>>(Pl, psum);
  k_fill<<<(ne+255)/256, 256, 0, stream>>>(cidx, lidx, Pc, Pl, clit, lcl, ne);

  for(int hop=0; hop<4; hop++){
    k_zero4<<<1, 256, 0, stream>>>((float4*)st, 128);
    k_clause_fused<<<37500, 64, 0, stream>>>(Pc, clit, Lh, CuW1, Cub1, CuW2, Cub2, C);
    k_colstats<<<512, 256, 0, stream>>>(C, st);
    k_finstats<<<1, 128, 0, stream>>>(st);
    k_lit_fused<<<25000, 64, 0, stream>>>(Pl, lcl, C, st, LuW1, Lub1, LuW2, Lub2, lng, lnb, Lh);
  }
  k_head_v<<<12500, 64, 0, stream>>>(Lh, VdW1, Vdb1, VdW2, Vdb2, VcW1, Vcb1, VcW2, Vcb2, out);
  k_head_c<<<37500, 64, 0, stream>>>(C, st, CsW1, Csb1, CsW2, Csb2, out + 200000);
}